// Round 7
// baseline (372.945 us; speedup 1.0000x reference)
//
#include <hip/hip_runtime.h>
#include <math.h>

typedef unsigned short u16;
typedef __bf16 bf16x8 __attribute__((ext_vector_type(8)));
typedef float f32x4 __attribute__((ext_vector_type(4)));
typedef short s16x8 __attribute__((ext_vector_type(8)));
typedef short s16x4 __attribute__((ext_vector_type(4)));

__device__ __forceinline__ float b2f(u16 u) {
    union { unsigned i; float f; } c; c.i = ((unsigned)u) << 16; return c.f;
}
__device__ __forceinline__ u16 f2b(float f) {
    union { float f; unsigned i; } c; c.f = f;
    return (u16)((c.i + 0x7fffu + ((c.i >> 16) & 1u)) >> 16);
}
__device__ __forceinline__ float gelu_f(float v) {
    return 0.5f * v * (1.0f + erff(v * 0.70710678118654752f));
}
__device__ __forceinline__ s16x8 cvt8(f32x4 a, f32x4 b) {
    s16x8 r;
    r[0] = (short)f2b(a[0]); r[1] = (short)f2b(a[1]);
    r[2] = (short)f2b(a[2]); r[3] = (short)f2b(a[3]);
    r[4] = (short)f2b(b[0]); r[5] = (short)f2b(b[1]);
    r[6] = (short)f2b(b[2]); r[7] = (short)f2b(b[3]);
    return r;
}
__device__ __forceinline__ void async_cp16(const u16* g, u16* l) {
    __builtin_amdgcn_global_load_lds((const __attribute__((address_space(1))) void*)g,
                                     (__attribute__((address_space(3))) void*)l, 16, 0, 0);
}

// ======== plain GEMM (fold kernels only), BK=64, 128x256 tiles ========
#define BK 64
template<int SUBN>
__global__ __launch_bounds__(256, 2)
void gemm_bt(const u16* __restrict__ A0, const u16* __restrict__ A1,
             const u16* __restrict__ W0, const u16* __restrict__ W1,
             const float* __restrict__ B0, const float* __restrict__ B1,
             void* __restrict__ O0v, void* __restrict__ O1v,
             int lda, int K, int halfBlocks, int ldo0, int ldo1,
             int mode0, int mode1)
{
    __shared__ u16 sA[128 * BK];
    __shared__ u16 sW[SUBN * 128 * BK];

    const int bx = blockIdx.x, by = blockIdx.y;
    const int half = (bx >= halfBlocks) ? 1 : 0;
    const int bxl = bx - half * halfBlocks;
    const u16* A = (half ? A1 : A0) + (size_t)by * 128 * lda;
    const u16* W = (half ? W1 : W0) + (size_t)bxl * (128 * SUBN) * K;
    const float* bias = half ? B1 : B0;
    void* outv = half ? O1v : O0v;
    const int ldo = half ? ldo1 : ldo0;
    const int mode = half ? mode1 : mode0;

    const int tid = threadIdx.x;
    const int lane = tid & 63;
    const int wave = tid >> 6;
    const int wm = (wave >> 1) * 64;
    const int wn = (wave & 1) * 64;
    const int fc = lane & 15;
    const int quad = lane >> 4;

    int pr[4], pc[4];
#pragma unroll
    for (int c = 0; c < 4; ++c) {
        const int p = tid + 256 * c;
        pr[c] = p >> 3;
        pc[c] = ((p & 7) - (pr[c] & 7)) & 7;
    }

    f32x4 acc[4][4 * SUBN];
#pragma unroll
    for (int i = 0; i < 4; ++i)
#pragma unroll
        for (int j = 0; j < 4 * SUBN; ++j)
            acc[i][j] = f32x4{0.f, 0.f, 0.f, 0.f};

    for (int k0 = 0; k0 < K; k0 += BK) {
#pragma unroll
        for (int c = 0; c < 4; ++c)
            async_cp16(A + (size_t)pr[c] * lda + k0 + pc[c] * 8, &sA[(tid + 256 * c) * 8]);
#pragma unroll
        for (int sub = 0; sub < SUBN; ++sub)
#pragma unroll
            for (int c = 0; c < 4; ++c)
                async_cp16(W + (size_t)(sub * 128 + pr[c]) * K + k0 + pc[c] * 8,
                           &sW[(sub * 1024 + tid + 256 * c) * 8]);
        __syncthreads();

#pragma unroll
        for (int kk = 0; kk < 2; ++kk) {
            bf16x8 af[4];
#pragma unroll
            for (int i = 0; i < 4; ++i) {
                const int ar = wm + i * 16 + fc;
                af[i] = *(const bf16x8*)&sA[(ar * 8 + ((kk * 4 + quad + (ar & 7)) & 7)) * 8];
            }
#pragma unroll
            for (int sub = 0; sub < SUBN; ++sub) {
#pragma unroll
                for (int j = 0; j < 4; ++j) {
                    const int wr = wn + j * 16 + fc;
                    bf16x8 wf = *(const bf16x8*)&sW[(sub * 1024 + wr * 8 + ((kk * 4 + quad + (wr & 7)) & 7)) * 8];
#pragma unroll
                    for (int i = 0; i < 4; ++i)
                        acc[i][sub * 4 + j] =
                            __builtin_amdgcn_mfma_f32_16x16x32_bf16(af[i], wf, acc[i][sub * 4 + j], 0, 0, 0);
                }
            }
        }
        __syncthreads();
    }

#pragma unroll
    for (int sub = 0; sub < SUBN; ++sub) {
#pragma unroll
        for (int j = 0; j < 4; ++j) {
            const int colh = bxl * (128 * SUBN) + sub * 128 + wn + j * 16 + fc;
            const float bv = bias[colh];
#pragma unroll
            for (int i = 0; i < 4; ++i) {
#pragma unroll
                for (int r = 0; r < 4; ++r) {
                    const int row = by * 128 + wm + i * 16 + quad * 4 + r;
                    const float v = acc[i][sub * 4 + j][r] + bv;
                    if (mode == 1)
                        ((float*)outv)[(size_t)row * ldo + colh] = 1.0f / (1.0f + expf(-v));
                    else
                        ((u16*)outv)[(size_t)row * ldo + colh] = f2b(v);
                }
            }
        }
    }
}

// ======== GEMM + fused LN, direct-L2 W loads, A dbuf, 1 barrier/iter ========
// Block: TM = MR*16 rows x TN = NW*CWT*16 cols (full row span of one half).
// NW waves = single row-group, each wave CWT*16 cols. BK = 32.
// W fragments load global->VGPR (L2-hot, 16 rows x 64B per load, no LDS).
// A double-buffered in LDS; one __syncthreads per K-iter; cp(t+1) issued
// AFTER wf(t) loads so the wf vmcnt wait does not drain the cp.
// mode 0: bf16 = LN(v)*g+beta ; 1: bf16 = gelu(LN(..)) ; 2: f32 sigmoid(v);
// mode 3: f32 = gelu(LN(..)) + attn := 1.0
template<int NW, int MR, int CWT, int AF32>
__global__ __launch_bounds__(NW * 64, 4)
void gemm_lnw(const void* __restrict__ A0v, const void* __restrict__ A1v,
              const u16* __restrict__ W0, const u16* __restrict__ W1,
              const float* __restrict__ B0, const float* __restrict__ B1,
              const float* __restrict__ G0, const float* __restrict__ G1f,
              const float* __restrict__ Be0, const float* __restrict__ Be1,
              void* __restrict__ O0v, void* __restrict__ O1v,
              int lda, int K, int halfBlocks, int ldo0, int ldo1,
              int mode0, int mode1,
              float* __restrict__ attn1, float* __restrict__ attn2)
{
    constexpr int TM = MR * 16;
    constexpr int CH = TM * 4;             // staging chunks per 32-K tile
    __shared__ u16 sA[2][TM * 32];         // 2 x (TM*32*2) bytes
    __shared__ float sred[2][NW][TM];

    const int bx = blockIdx.x, by = blockIdx.y;
    const int half = (bx >= halfBlocks) ? 1 : 0;
    const u16* W = half ? W1 : W0;
    const float* bias = half ? B1 : B0;
    const float* gain = half ? G1f : G0;
    const float* beta = half ? Be1 : Be0;
    void* outv = half ? O1v : O0v;
    const int ldo = half ? ldo1 : ldo0;
    const int mode = half ? mode1 : mode0;

    const int tid = threadIdx.x;
    const int lane = tid & 63;
    const int wave = tid >> 6;
    const int fc = lane & 15;
    const int quad = lane >> 4;
    const int wn = wave * (CWT * 16);

    // A sources: AF32 -> concat [text|num] f32 (lda ignored); else bf16 per half
    const float* Atxt = (const float*)A0v + (size_t)by * TM * 256;
    const float* Anum = (const float*)A1v + (size_t)by * TM * 256;
    const u16* Ab = (const u16*)(half ? A1v : A0v) + (size_t)by * TM * lda;

    // R5/R6-proven BK=32 swizzle: chunk p holds (r=p>>2, k8=((p&3)-(r>>1))&3);
    // frag read slot = r*4 + ((quad+(r>>1))&3)
    const int pr = tid >> 2, pc = ((tid & 3) - (pr >> 1)) & 3;
    const bool stager = tid < CH;

    const u16* wp[CWT];
#pragma unroll
    for (int j = 0; j < CWT; ++j)
        wp[j] = W + (size_t)(wn + j * 16 + fc) * K + quad * 8;

    f32x4 acc[MR][CWT];
#pragma unroll
    for (int i = 0; i < MR; ++i)
#pragma unroll
        for (int j = 0; j < CWT; ++j)
            acc[i][j] = f32x4{0.f, 0.f, 0.f, 0.f};

    // stage tile 0 into buffer 0
    if (stager) {
        if (AF32) {
            const int col = pc * 8;
            const float* src = (col < 256) ? Atxt + (size_t)pr * 256 + col
                                           : Anum + (size_t)pr * 256 + (col - 256);
            *(s16x8*)&sA[0][tid * 8] = cvt8(*(const f32x4*)src, *(const f32x4*)(src + 4));
        } else {
            async_cp16(Ab + (size_t)pr * lda + pc * 8, &sA[0][tid * 8]);
        }
    }

    const int T = K >> 5;
    for (int t = 0; t < T; ++t) {
        const int cur = t & 1;
        __syncthreads();                       // tile t staged; other buffer free
        // W fragments for tile t (VMEM first -> precise waits, no cp drain)
        bf16x8 wf[CWT];
#pragma unroll
        for (int j = 0; j < CWT; ++j)
            wf[j] = *(const bf16x8*)(wp[j] + t * 32);
        // stage tile t+1 into the other buffer
        if (t + 1 < T && stager) {
            const int kg = (t + 1) * 32 + pc * 8;
            if (AF32) {
                const float* src = (kg < 256) ? Atxt + (size_t)pr * 256 + kg
                                              : Anum + (size_t)pr * 256 + (kg - 256);
                *(s16x8*)&sA[cur ^ 1][tid * 8] = cvt8(*(const f32x4*)src, *(const f32x4*)(src + 4));
            } else {
                async_cp16(Ab + (size_t)pr * lda + kg, &sA[cur ^ 1][tid * 8]);
            }
        }
        bf16x8 af[MR];
#pragma unroll
        for (int i = 0; i < MR; ++i) {
            const int ar = i * 16 + fc;
            af[i] = *(const bf16x8*)&sA[cur][(ar * 4 + ((quad + (ar >> 1)) & 3)) * 8];
        }
#pragma unroll
        for (int j = 0; j < CWT; ++j)
#pragma unroll
            for (int i = 0; i < MR; ++i)
                acc[i][j] = __builtin_amdgcn_mfma_f32_16x16x32_bf16(af[i], wf[j], acc[i][j], 0, 0, 0);
    }

    // bias add
#pragma unroll
    for (int j = 0; j < CWT; ++j) {
        const float bv = bias[wn + j * 16 + fc];
#pragma unroll
        for (int i = 0; i < MR; ++i)
#pragma unroll
            for (int r = 0; r < 4; ++r)
                acc[i][j][r] += bv;
    }

    if (mode == 2) {                           // sigmoid, no LN
#pragma unroll
        for (int j = 0; j < CWT; ++j) {
            const int col = wn + j * 16 + fc;
#pragma unroll
            for (int i = 0; i < MR; ++i)
#pragma unroll
                for (int r = 0; r < 4; ++r) {
                    const int row = by * TM + i * 16 + quad * 4 + r;
                    ((float*)outv)[(size_t)row * ldo + col] =
                        1.0f / (1.0f + expf(-acc[i][j][r]));
                }
        }
        return;
    }

    // per-row partial stats over this wave's cols; 16-lane shfl reduce
#pragma unroll
    for (int i = 0; i < MR; ++i)
#pragma unroll
        for (int r = 0; r < 4; ++r) {
            float s = 0.f, ss = 0.f;
#pragma unroll
            for (int j = 0; j < CWT; ++j) { const float v = acc[i][j][r]; s += v; ss += v * v; }
#pragma unroll
            for (int m = 1; m <= 8; m <<= 1) { s += __shfl_xor(s, m); ss += __shfl_xor(ss, m); }
            if (fc == 0) {
                sred[0][wave][i * 16 + quad * 4 + r] = s;
                sred[1][wave][i * 16 + quad * 4 + r] = ss;
            }
        }
    __syncthreads();

    constexpr float invTN = 1.0f / (NW * CWT * 16);
    float gv[CWT], bev[CWT];
#pragma unroll
    for (int j = 0; j < CWT; ++j) {
        gv[j] = gain[wn + j * 16 + fc];
        bev[j] = beta[wn + j * 16 + fc];
    }

#pragma unroll
    for (int i = 0; i < MR; ++i)
#pragma unroll
        for (int r = 0; r < 4; ++r) {
            const int rl = i * 16 + quad * 4 + r;
            float S = 0.f, SS = 0.f;
#pragma unroll
            for (int w = 0; w < NW; ++w) { S += sred[0][w][rl]; SS += sred[1][w][rl]; }
            const float mean = S * invTN;
            const float var = SS * invTN - mean * mean;
            const float rs = rsqrtf(var + 1e-5f);
            const int row = by * TM + rl;
#pragma unroll
            for (int j = 0; j < CWT; ++j) {
                const int col = wn + j * 16 + fc;
                float y = (acc[i][j][r] - mean) * rs * gv[j] + bev[j];
                if (mode != 0) y = gelu_f(y);
                if (mode == 3)
                    ((float*)outv)[(size_t)row * ldo + col] = y;
                else
                    ((u16*)outv)[(size_t)row * ldo + col] = f2b(y);
            }
        }
    if (mode == 3 && tid < TM) {
        attn1[by * TM + tid] = 1.0f;
        attn2[by * TM + tid] = 1.0f;
    }
}

// ======== prep (weights only; EMB cvt folded into G1') ========

__device__ __forceinline__ void cvt_quads(const float* __restrict__ src,
                                          u16* __restrict__ dst, int bi, int tid)
{
#pragma unroll
    for (int c = 0; c < 2; ++c) {
        const int q = bi * 512 + tid + 256 * c;
        f32x4 v = *(const f32x4*)(src + (size_t)q * 4);
        s16x4 o;
        o[0] = (short)f2b(v[0]); o[1] = (short)f2b(v[1]);
        o[2] = (short)f2b(v[2]); o[3] = (short)f2b(v[3]);
        *(s16x4*)(dst + (size_t)q * 4) = o;
    }
}

__device__ void transpose_cvt64(const float* __restrict__ src, int C,
                                u16* __restrict__ dst, int R,
                                int tr, int tc, int tid, float* sm)
{
    const int lr = tid >> 4, lc4 = (tid & 15) * 4;
#pragma unroll
    for (int m = 0; m < 4; ++m) {
        const int i = lr + m * 16;
        f32x4 v = *(const f32x4*)&src[(size_t)(tr + i) * C + tc + lc4];
#pragma unroll
        for (int mm = 0; mm < 4; ++mm) sm[i * 65 + lc4 + mm] = v[mm];
    }
    __syncthreads();
#pragma unroll
    for (int m = 0; m < 4; ++m) {
        const int j = lr + m * 16;
        s16x4 o;
#pragma unroll
        for (int mm = 0; mm < 4; ++mm)
            o[mm] = (short)f2b(sm[(size_t)(lc4 + mm) * 65 + j]);
        *(s16x4*)&dst[(size_t)(tc + j) * R + tr + lc4] = o;
    }
}

__device__ void matvec_rows(const float* __restrict__ M, const float* __restrict__ v,
                            const float* __restrict__ add1, const float* __restrict__ add2,
                            float* __restrict__ out, int r0, int tid, float* sm)
{
    for (int i = tid; i < 512; i += 256) sm[i] = v[i];
    __syncthreads();
    const int row = r0 + (tid & 63), q = tid >> 6;
    float s = 0.f;
    for (int k = q * 128; k < q * 128 + 128; k += 4) {
        f32x4 m = *(const f32x4*)&M[(size_t)row * 512 + k];
        s += m[0] * sm[k] + m[1] * sm[k + 1] + m[2] * sm[k + 2] + m[3] * sm[k + 3];
    }
    sm[512 + tid] = s;
    __syncthreads();
    if (tid < 64)
        out[r0 + tid] = sm[512 + tid] + sm[512 + tid + 64] + sm[512 + tid + 128] +
                        sm[512 + tid + 192] + add1[r0 + tid] + add2[r0 + tid];
}

__global__ __launch_bounds__(256)
void prep_cvt(const float* __restrict__ tp_w, const float* __restrict__ np_w,
              const float* __restrict__ g_w, const float* __restrict__ m1_w,
              const float* __restrict__ m2_w,
              const float* __restrict__ a1_wv, const float* __restrict__ a2_wv,
              const float* __restrict__ a1_wo, const float* __restrict__ a2_wo,
              const float* __restrict__ a1_bv, const float* __restrict__ a1_bo,
              const float* __restrict__ a2_bv, const float* __restrict__ a2_bo,
              const float* __restrict__ tp_b, const float* __restrict__ np_b,
              u16* __restrict__ Wbig,
              u16* __restrict__ g_bf, u16* __restrict__ m1_bf, u16* __restrict__ m2_bf,
              u16* __restrict__ a1_wvT, u16* __restrict__ a2_wvT,
              u16* __restrict__ tp_wT, u16* __restrict__ np_wT,
              u16* __restrict__ a1_wo_bf, u16* __restrict__ a2_wo_bf,
              float* __restrict__ w1, float* __restrict__ w2,
              float* __restrict__ zb)
{
    __shared__ float smem[64 * 65];
    const int b = blockIdx.x, tid = threadIdx.x;
    if (b < 256) { cvt_quads(g_w, g_bf, b, tid); }
    else if (b < 512) { cvt_quads(m1_w, m1_bf, b - 256, tid); }
    else if (b < 576) { cvt_quads(m2_w, m2_bf, b - 512, tid); }
    else if (b < 640) {                   // np_w -> Wbig[0:512, 256:512]
#pragma unroll
        for (int c = 0; c < 2; ++c) {
            const int q = (b - 576) * 512 + tid + 256 * c;
            const int e = q * 4, row = e >> 8, col = e & 255;
            f32x4 v = *(const f32x4*)(np_w + e);
            s16x4 o;
            o[0] = (short)f2b(v[0]); o[1] = (short)f2b(v[1]);
            o[2] = (short)f2b(v[2]); o[3] = (short)f2b(v[3]);
            *(s16x4*)(Wbig + (size_t)row * 512 + 256 + col) = o;
        }
    } else if (b < 704) {                 // tp_w -> Wbig[512:1024, 0:256]
#pragma unroll
        for (int c = 0; c < 2; ++c) {
            const int q = (b - 640) * 512 + tid + 256 * c;
            const int e = q * 4, row = e >> 8, col = e & 255;
            f32x4 v = *(const f32x4*)(tp_w + e);
            s16x4 o;
            o[0] = (short)f2b(v[0]); o[1] = (short)f2b(v[1]);
            o[2] = (short)f2b(v[2]); o[3] = (short)f2b(v[3]);
            *(s16x4*)(Wbig + (size_t)(512 + row) * 512 + col) = o;
        }
    } else if (b < 768) {
        const int t = b - 704;
        transpose_cvt64(a1_wv, 512, a1_wvT, 512, (t >> 3) * 64, (t & 7) * 64, tid, smem);
    } else if (b < 832) {
        const int t = b - 768;
        transpose_cvt64(a2_wv, 512, a2_wvT, 512, (t >> 3) * 64, (t & 7) * 64, tid, smem);
    } else if (b < 864) {
        const int t = b - 832;
        transpose_cvt64(tp_w, 256, tp_wT, 512, (t >> 2) * 64, (t & 3) * 64, tid, smem);
    } else if (b < 896) {
        const int t = b - 864;
        transpose_cvt64(np_w, 256, np_wT, 512, (t >> 2) * 64, (t & 3) * 64, tid, smem);
    } else if (b < 1024) { cvt_quads(a1_wo, a1_wo_bf, b - 896, tid); }
    else if (b < 1152) { cvt_quads(a2_wo, a2_wo_bf, b - 1024, tid); }
    else if (b < 1160) {
        matvec_rows(a1_wo, a1_bv, a1_bo, np_b, w1, (b - 1152) * 64, tid, smem);
    } else if (b < 1168) {
        matvec_rows(a2_wo, a2_bv, a2_bo, tp_b, w2, (b - 1160) * 64, tid, smem);
    } else {
        *(f32x4*)&zb[tid * 4] = f32x4{0.f, 0.f, 0.f, 0.f};
    }
}

__global__ __launch_bounds__(256)
void prep_bias(const u16* __restrict__ M1, const u16* __restrict__ M2,
               const float* __restrict__ tp_b, const float* __restrict__ np_b,
               const float* __restrict__ w1, const float* __restrict__ w2,
               float* __restrict__ bbig)
{
    __shared__ float sm[768];
    const int b = blockIdx.x, tid = threadIdx.x;
    const int side = b >> 3, r0 = (b & 7) * 64;
    const u16* M = side ? M2 : M1;
    const float* v = side ? np_b : tp_b;
    const float* w = side ? w2 : w1;
    float* out = bbig + side * 512;
    for (int i = tid; i < 512; i += 256) sm[i] = v[i];
    __syncthreads();
    const int row = r0 + (tid & 63), q = tid >> 6;
    float s = 0.f;
    for (int k = q * 128; k < q * 128 + 128; k += 8) {
        s16x8 m = *(const s16x8*)&M[(size_t)row * 512 + k];
#pragma unroll
        for (int j = 0; j < 8; ++j) s += b2f((u16)m[j]) * sm[k + j];
    }
    sm[512 + tid] = s;
    __syncthreads();
    if (tid < 64)
        out[r0 + tid] = sm[512 + tid] + sm[512 + tid + 64] + sm[512 + tid + 128] +
                        sm[512 + tid + 192] + w[r0 + tid];
}

extern "C" void kernel_launch(void* const* d_in, const int* in_sizes, int n_in,
                              void* d_out, int out_size, void* d_ws, size_t ws_size,
                              hipStream_t stream)
{
    const float* text  = (const float*)d_in[0];
    const float* num   = (const float*)d_in[1];
    const float* tp_w  = (const float*)d_in[2];
    const float* tp_b  = (const float*)d_in[3];
    const float* np_w  = (const float*)d_in[4];
    const float* np_b  = (const float*)d_in[5];
    const float* a1_wv = (const float*)d_in[8];
    const float* a1_bv = (const float*)d_in[11];
    const float* a1_wo = (const float*)d_in[12];
    const float* a1_bo = (const float*)d_in[13];
    const float* a2_wv = (const float*)d_in[16];
    const float* a2_bv = (const float*)d_in[19];
    const float* a2_wo = (const float*)d_in[20];
    const float* a2_bo = (const float*)d_in[21];
    const float* n1_g  = (const float*)d_in[22];
    const float* n1_b  = (const float*)d_in[23];
    const float* n2_g  = (const float*)d_in[24];
    const float* n2_b  = (const float*)d_in[25];
    const float* g_w   = (const float*)d_in[26];
    const float* g_b   = (const float*)d_in[27];
    const float* m1_w  = (const float*)d_in[28];
    const float* m1_b  = (const float*)d_in[29];
    const float* ln1_g = (const float*)d_in[30];
    const float* ln1_b = (const float*)d_in[31];
    const float* m2_w  = (const float*)d_in[32];
    const float* m2_b  = (const float*)d_in[33];
    const float* ln2_g = (const float*)d_in[34];
    const float* ln2_b = (const float*)d_in[35];

    float* outp = (float*)d_out;
    char* ws = (char*)d_ws;
    const size_t KB = 1024, MB = 1048576;

    // ws: comb [0,32MB), h [32,48MB), weight scratch [48MB,...)
    u16* comb = (u16*)ws;                            // [16384 x 1024] bf16
    u16* h    = (u16*)(ws + 32 * MB);                // [16384 x 512] bf16
    char* sc  = ws + 48 * MB;
    u16* Wbig     = (u16*)(sc);                      // 1 MB [1024x512]
    u16* g_bf     = (u16*)(sc + 1 * MB);             // 1 MB [512x1024]
    u16* m1_bf    = (u16*)(sc + 2 * MB);             // 1 MB [512x1024]
    u16* m2_bf    = (u16*)(sc + 3 * MB);             // 256 KB [256x512]
    u16* a1_wvT   = (u16*)(sc + 3 * MB + 256 * KB);  // 512 KB
    u16* a2_wvT   = (u16*)(sc + 3 * MB + 768 * KB);  // 512 KB
    u16* tp_wT    = (u16*)(sc + 4 * MB + 256 * KB);  // 256 KB [256x512]
    u16* np_wT    = (u16*)(sc + 4 * MB + 512 * KB);  // 256 KB
    u16* a1_wo_bf = (u16*)(sc + 4 * MB + 768 * KB);  // 512 KB
    u16* a2_wo_bf = (u16*)(sc + 5 * MB + 256 * KB);  // 512 KB
    u16* M1       = (u16*)(sc + 5 * MB + 768 * KB);  // 512 KB
    u16* M2       = (u16*)(sc + 6 * MB + 256 * KB);  // 512 KB
    float* w1     = (float*)(sc + 6 * MB + 768 * KB);
    float* w2     = w1 + 512;
    float* bbig   = w1 + 1024;
    float* zb     = w1 + 2048;

    float* gate_out = outp + (size_t)16384 * 256;    // [B,512] f32
    float* attn1 = outp + (size_t)16384 * 768;
    float* attn2 = outp + (size_t)16384 * 768 + 16384;

    dim3 blk(256);

    // P1: weight conversions, transposes, w1/w2, zbias (~12 MB, memory-bound)
    prep_cvt<<<1169, blk, 0, stream>>>(tp_w, np_w, g_w, m1_w, m2_w,
        a1_wv, a2_wv, a1_wo, a2_wo, a1_bv, a1_bo, a2_bv, a2_bo, tp_b, np_b,
        Wbig, g_bf, m1_bf, m2_bf, a1_wvT, a2_wvT, tp_wT, np_wT,
        a1_wo_bf, a2_wo_bf, w1, w2, zb);
    // F1: M1 = a1_wo@a1_wv ; M2 = a2_wo@a2_wv
    gemm_bt<2><<<dim3(4, 4), blk, 0, stream>>>(a1_wo_bf, a2_wo_bf, a1_wvT, a2_wvT,
        zb, zb, M1, M2, 512, 512, 2, 512, 512, 0, 0);
    // PB: bbig = [M1@tp_b + w1 | M2@np_b + w2]
    prep_bias<<<16, blk, 0, stream>>>(M1, M2, tp_b, np_b, w1, w2, bbig);
    // F2: Wbig[0:512,0:256] = M1@tp_w ; Wbig[512:,256:] = M2@np_w
    gemm_bt<2><<<dim3(2, 4), blk, 0, stream>>>(M1, M2, tp_wT, np_wT,
        zb, zb, Wbig, Wbig + (size_t)512 * 512 + 256, 512, 512, 1, 512, 512, 0, 0);
    // G1': comb = [LN([t|n]@WbigL.T + bL)*n1 | LN(..R..)*n2]; A = f32 text/num
    gemm_lnw<8, 4, 4, 1><<<dim3(2, 256), dim3(512), 0, stream>>>(text, num,
        Wbig, Wbig + (size_t)512 * 512, bbig, bbig + 512,
        n1_g, n2_g, n1_b, n2_b, comb, comb + 512,
        512, 512, 1, 1024, 1024, 0, 0, nullptr, nullptr);
    // G2': gate = sigmoid(comb@g_w.T+g_b) f32 ; h = gelu(LN(comb@m1_w.T+m1_b)*ln1)
    gemm_lnw<8, 4, 4, 0><<<dim3(2, 256), dim3(512), 0, stream>>>(comb, comb,
        g_bf, m1_bf, g_b, m1_b, ln1_g, ln1_g, ln1_b, ln1_b, gate_out, h,
        1024, 1024, 1, 512, 512, 2, 1, nullptr, nullptr);
    // G3': fused = gelu(LN(h@m2_w.T+m2_b)*ln2) f32 -> d_out; attn := 1.0
    gemm_lnw<4, 2, 4, 0><<<dim3(1, 512), dim3(256), 0, stream>>>(h, h,
        m2_bf, m2_bf, m2_b, m2_b, ln2_g, ln2_g, ln2_b, ln2_b, outp, outp,
        512, 512, 1, 256, 256, 3, 3, attn1, attn2);
}